// Round 1
// baseline (331.347 us; speedup 1.0000x reference)
//
#include <hip/hip_runtime.h>
#include <hip/hip_fp16.h>
#include <stddef.h>

// Problem: N=4, S=4096, E=1024, H=16, D=64. fp32 in/out.
// Reference = "attention over heads": per (n,s) position, 16x16 softmax across
// heads, then scrambled (N,H,S,D)->(N,S,E) reshape + output projection.
// Pipeline (f16 MFMA compute, fp32 accumulate; absmax ~8e-3 << 4.09e-2):
//   K0: convert x, Wq..Wo fp32 -> f16 in ws
//   K1: QKV projections (3x GEMM 16384x1024x1024 NT +bias) -> ws f16
//   K2: per-position head-attention, ONE WAVE per position (unchanged)
//   K3: output projection -> fp32 out
// GEMM core THIS ROUND: 256x256 tile, BK=64, 8 waves, 8-phase schedule
// (T2 swizzle + T3/T4 counted vmcnt + T5 setprio + T1 XCD swizzle), replacing
// the m97 128^2 structure (~900 TF ceiling) with the ~1563-1728 TF template.

typedef _Float16 f16_t;
typedef _Float16 f16x8 __attribute__((ext_vector_type(8)));
typedef _Float16 f16x4 __attribute__((ext_vector_type(4)));
typedef float    f32x4 __attribute__((ext_vector_type(4)));

static constexpr int Sdim = 4096;
static constexpr int Edim = 1024;
static constexpr int Mrows = 4 * Sdim;                  // 16384
static constexpr size_t MATEL = (size_t)Mrows * Edim;   // 16.7M
static constexpr size_t WEL = (size_t)Edim * Edim;      // 1.05M

__device__ __forceinline__ void gload_lds16(const f16_t* g, f16_t* l) {
  // async global->LDS, 16B/lane; LDS dest = wave-uniform base + lane*16
  __builtin_amdgcn_global_load_lds(
      (const __attribute__((address_space(1))) void*)g,
      (__attribute__((address_space(3))) void*)l, 16, 0, 0);
}

// ---------------- fp32 -> f16 convert ----------------
__global__ __launch_bounds__(256) void cvt_kernel(
    const float* __restrict__ s0, const float* __restrict__ s1,
    const float* __restrict__ s2, const float* __restrict__ s3,
    const float* __restrict__ s4,
    f16_t* __restrict__ d0, f16_t* __restrict__ d1, f16_t* __restrict__ d2,
    f16_t* __restrict__ d3, f16_t* __restrict__ d4) {
  const float* s; f16_t* d; size_t nv;  // nv = count of float4 groups
  switch (blockIdx.y) {
    case 0: s = s0; d = d0; nv = MATEL / 4; break;
    case 1: s = s1; d = d1; nv = WEL / 4; break;
    case 2: s = s2; d = d2; nv = WEL / 4; break;
    case 3: s = s3; d = d3; nv = WEL / 4; break;
    default: s = s4; d = d4; nv = WEL / 4; break;
  }
  const size_t stride = (size_t)gridDim.x * 256;
  for (size_t i = blockIdx.x * 256 + threadIdx.x; i < nv; i += stride) {
    const f32x4 v = ((const f32x4*)s)[i];
    f16x4 h;
#pragma unroll
    for (int j = 0; j < 4; j++) h[j] = (f16_t)v[j];
    ((f16x4*)d)[i] = h;
  }
}

// ---------------- 256^2 8-phase GEMM core ----------------
// C[m,n] = sum_k A[m,k]*B[n,k] + bias[n]  (NT, both row-major stride Edim)
// 512 threads = 8 waves (2M x 4N). Per wave: 128x64 output = acc[8][4] f32x4.
// LDS 128 KiB: [slot][mat A/B][half 128x64] double-buffered at K-tile (BK=64)
// granularity. Swizzle: logical (r,c) stored at f16 idx r*64 + (c ^ ((r&7)<<3))
// -> ds_read_b128 of a fragment column spreads 16 rows over 8 16B slots (2-way,
// free per m136). global_load_lds writes LINEARLY; the same involution is
// applied to the per-lane GLOBAL source column instead (rule #21).
static constexpr int BM2 = 256, BN2 = 256, BK2 = 64;
static constexpr int NT2 = Edim / BK2;   // 16 K-tiles
static constexpr int HALF2 = 128 * BK2;  // 8192 f16 = 16KB per half-tile

template <int V> struct ic { static constexpr int v = V; };

template <typename TOut>
__device__ __forceinline__ void gemm256(const f16_t* __restrict__ A,
                                        const f16_t* __restrict__ B,
                                        const float* __restrict__ bias,
                                        TOut* __restrict__ C) {
  __shared__ __align__(16) f16_t lds[2][2][2][HALF2];  // [slot][mat][half][.]

  const int t = threadIdx.x;
  const int lane = t & 63;
  const int w = t >> 6;
  const int l16 = lane & 15;
  const int quad = lane >> 4;
  const int ha = w >> 2;         // A half this wave reads (wm = ha*128)
  const int hb = (w & 3) >> 1;   // B half this wave reads
  const int wnr = (w & 1) * 64;  // row offset inside B half

  // T1: XCD-chunked bijective swizzle over the 256 (mtile,ntile) blocks.
  // id2 = nt*64 + mt: each XCD gets 32 consecutive ids -> one W-panel (2MB,
  // L2-resident) + contiguous A rows.
  const int id = blockIdx.x;
  const int id2 = (id & 7) * 32 + (id >> 3);
  const int bm = (id2 & 63) * BM2;
  const int bn = (id2 >> 6) * BN2;

  // Staging geometry: per half-tile, 2 issues/wave, 1KB/wave/issue (linear).
  // Physical f16 idx (in half) = w*512 + issue*4096 + lane*8
  //   -> row r = w*8 + issue*64 + lane/8, phys col = (lane&7)*8.
  // Inverse-swizzled global col = ((lane&7) ^ ((lane>>3)&7)) * 8.
  const int srow = w * 8 + (lane >> 3);
  const int scol = ((lane & 7) ^ ((lane >> 3) & 7)) * 8;
  const size_t gA0 = (size_t)(bm + srow) * Edim + scol;
  const size_t gB0 = (size_t)(bn + srow) * Edim + scol;
  const int lws = w * 512 + lane * 8;

  auto stage = [&](int mat, int half, int slot, int kt) {
    const f16_t* g = (mat == 0 ? A + gA0 : B + gB0) +
                     (size_t)half * 128 * Edim + kt * BK2;
    f16_t* l = &lds[slot][mat][half][lws];
    gload_lds16(g, l);                          // rows 0..63 of half
    gload_lds16(g + (size_t)64 * Edim, l + 4096);  // rows 64..127
  };

  f32x4 acc[8][4] = {};

  // Prologue: tile0 (A0,A1,B0,B1) + B(1). vmcnt(4) -> all of tile0 landed.
  stage(0, 0, 0, 0); stage(0, 1, 0, 0);
  stage(1, 0, 0, 0); stage(1, 1, 0, 0);
  stage(1, 0, 1, 1); stage(1, 1, 1, 1);
  asm volatile("s_waitcnt vmcnt(4)" ::: "memory");
  __builtin_amdgcn_s_barrier();
  asm volatile("" ::: "memory");

  // One K-tile = 4 phases: (kc0,ih0)(kc0,ih1)(kc1,ih0)(kc1,ih1).
  // ds-reads: P1 = 8 B-frags (both kc) + 4 A-frags; P2-P4 = 4 A-frags each.
  // Stage schedule (write-safety proven vs barrier placement):
  //   P1: A0(t+1)->slot^1   (slot^1 A last read at t-1's P4, barrier'd)
  //   P2: A1(t+1)->slot^1
  //   P3: B0(t+2)->slot     (slot B last read at THIS tile's P1, barrier'd)
  //   P4: B1(t+2)->slot, then vmcnt(4): leaves only B(t+2) in flight
  //       -> A(t+1), B(t+1) guaranteed landed before tile t+1's P1 reads.
  auto ktile = [&](int tt, auto Sc, auto SAc, auto SBc, auto VNc) {
    constexpr int S = decltype(Sc)::v;
    constexpr int SA = decltype(SAc)::v;   // stage A(t+1)?
    constexpr int SB = decltype(SBc)::v;   // stage B(t+2)?
    constexpr int VN = decltype(VNc)::v;   // 1 -> vmcnt(4), 0 -> vmcnt(0)
    const f16_t* Ah = &lds[S][0][ha][0];
    const f16_t* Bh = &lds[S][1][hb][0];
    f16x8 bf[2][4];
#pragma unroll
    for (int kc = 0; kc < 2; ++kc) {
#pragma unroll
      for (int ih = 0; ih < 2; ++ih) {
        if (kc == 0 && ih == 0) {
#pragma unroll
          for (int kk = 0; kk < 2; ++kk)
#pragma unroll
            for (int j = 0; j < 4; ++j) {
              const int r = wnr + j * 16 + l16;
              bf[kk][j] = *(const f16x8*)
                  &Bh[r * 64 + ((kk * 32 + quad * 8) ^ ((r & 7) << 3))];
            }
        }
        f16x8 af[4];
#pragma unroll
        for (int ii = 0; ii < 4; ++ii) {
          const int r = ih * 64 + ii * 16 + l16;
          af[ii] = *(const f16x8*)
              &Ah[r * 64 + ((kc * 32 + quad * 8) ^ ((r & 7) << 3))];
        }
        if (kc == 0 && ih == 0) { if (SA) stage(0, 0, S ^ 1, tt + 1); }
        if (kc == 0 && ih == 1) { if (SA) stage(0, 1, S ^ 1, tt + 1); }
        if (kc == 1 && ih == 0) { if (SB) stage(1, 0, S, tt + 2); }
        if (kc == 1 && ih == 1) {
          if (SB) stage(1, 1, S, tt + 2);
          if (VN) asm volatile("s_waitcnt vmcnt(4)" ::: "memory");
          else    asm volatile("s_waitcnt vmcnt(0)" ::: "memory");
        }
        asm volatile("" ::: "memory");
        __builtin_amdgcn_s_barrier();
        asm volatile("s_waitcnt lgkmcnt(0)" ::: "memory");
        __builtin_amdgcn_sched_barrier(0);
        __builtin_amdgcn_s_setprio(1);
#pragma unroll
        for (int ii = 0; ii < 4; ++ii)
#pragma unroll
          for (int j = 0; j < 4; ++j)
            acc[ih * 4 + ii][j] = __builtin_amdgcn_mfma_f32_16x16x32_f16(
                af[ii], bf[kc][j], acc[ih * 4 + ii][j], 0, 0, 0);
        __builtin_amdgcn_s_setprio(0);
        __builtin_amdgcn_s_barrier();
        asm volatile("" ::: "memory");
      }
    }
  };

  for (int it = 0; it < NT2 / 2 - 1; ++it) {   // tiles 0..13, full pipeline
    ktile(2 * it,     ic<0>{}, ic<1>{}, ic<1>{}, ic<1>{});
    ktile(2 * it + 1, ic<1>{}, ic<1>{}, ic<1>{}, ic<1>{});
  }
  // Tail: tile 14 still stages A(15); no B stage; drain to vmcnt(0).
  ktile(NT2 - 2, ic<0>{}, ic<1>{}, ic<0>{}, ic<0>{});
  ktile(NT2 - 1, ic<1>{}, ic<0>{}, ic<0>{}, ic<0>{});

  // Epilogue. C/D layout: col = lane&15, row = quad*4 + reg [m89-verified].
  // acc[i][j]: global row = bm + ha*128 + i*16 + quad*4 + r (i = ih*4+ii,
  // (ih*64 + ii*16) == i*16), col = bn + (w&3)*64 + j*16 + l16.
  const int wm = ha * 128;
  const int wn = (w & 3) * 64;
#pragma unroll
  for (int j = 0; j < 4; ++j) {
    const int col = bn + wn + j * 16 + l16;
    const float bv = bias[col];
#pragma unroll
    for (int i = 0; i < 8; ++i) {
      const int rb = bm + wm + i * 16 + quad * 4;
#pragma unroll
      for (int r = 0; r < 4; ++r)
        C[(size_t)(rb + r) * Edim + col] = (TOut)(acc[i][j][r] + bv);
    }
  }
}

__global__ __launch_bounds__(512, 2) void qkv_kernel(
    const f16_t* __restrict__ x,
    const f16_t* __restrict__ Wq, const float* __restrict__ bq,
    const f16_t* __restrict__ Wk, const float* __restrict__ bk,
    const f16_t* __restrict__ Wv, const float* __restrict__ bv,
    f16_t* __restrict__ Qb, f16_t* __restrict__ Kb, f16_t* __restrict__ Vb) {
  const f16_t* W; const float* bi; f16_t* C;
  if (blockIdx.z == 0)      { W = Wq; bi = bq; C = Qb; }
  else if (blockIdx.z == 1) { W = Wk; bi = bk; C = Kb; }
  else                      { W = Wv; bi = bv; C = Vb; }
  gemm256<f16_t>(x, W, bi, C);
}

__global__ __launch_bounds__(512, 2) void outp_kernel(
    const f16_t* __restrict__ Ab, const f16_t* __restrict__ Wo,
    const float* __restrict__ bo, float* __restrict__ out) {
  gemm256<float>(Ab, Wo, bo, out);
}

// ---------------- per-position head-attention (one wave / position) ----------
// (unchanged from verified 348us kernel)
__global__ __launch_bounds__(256) void attn_kernel(const f16_t* __restrict__ Qb,
                                                   const f16_t* __restrict__ Kb,
                                                   const f16_t* __restrict__ Vb,
                                                   f16_t* __restrict__ Ab) {
  __shared__ __align__(16) f16_t Vs[4][1024];  // per-wave V row (2KB each)
  const int t = threadIdx.x;
  const int w = t >> 6;
  const int lane = t & 63;
  const int l16 = lane & 15;
  const int quad = lane >> 4;
  const int pos = blockIdx.x * 4 + w;           // n*S + s
  const int n4 = pos >> 12;
  const int s = pos & (Sdim - 1);

  const f16_t* Qr = Qb + (size_t)pos * Edim;
  const f16_t* Kr = Kb + (size_t)pos * Edim;
  const f16_t* Vr = Vb + (size_t)pos * Edim;

  *(f16x8*)&Vs[w][lane * 16]     = *(const f16x8*)(Vr + lane * 16);
  *(f16x8*)&Vs[w][lane * 16 + 8] = *(const f16x8*)(Vr + lane * 16 + 8);

  f32x4 sacc = {};
#pragma unroll
  for (int step = 0; step < 2; step++) {
    const int off = l16 * 64 + step * 32 + quad * 8;
    const f16x8 kf = *(const f16x8*)(Kr + off);  // A: K[m=l16][k]
    const f16x8 qf = *(const f16x8*)(Qr + off);  // B: Q[n=l16][k]
    sacc = __builtin_amdgcn_mfma_f32_16x16x32_f16(kf, qf, sacc, 0, 0, 0);
  }
#pragma unroll
  for (int r = 0; r < 4; r++) sacc[r] *= 0.125f;

  float m = fmaxf(fmaxf(sacc[0], sacc[1]), fmaxf(sacc[2], sacc[3]));
  m = fmaxf(m, __shfl_xor(m, 16));
  m = fmaxf(m, __shfl_xor(m, 32));
  float e[4];
#pragma unroll
  for (int r = 0; r < 4; r++) e[r] = __expf(sacc[r] - m);
  float l = (e[0] + e[1]) + (e[2] + e[3]);
  l += __shfl_xor(l, 16);
  l += __shfl_xor(l, 32);
  const float inv = 1.0f / l;
  f16x4 pa;
#pragma unroll
  for (int r = 0; r < 4; r++) pa[r] = (f16_t)(e[r] * inv);

  __syncthreads();
  f32x4 oacc[4];
#pragma unroll
  for (int dc = 0; dc < 4; dc++) {
    f16x4 vbf;
#pragma unroll
    for (int j = 0; j < 4; j++)
      vbf[j] = Vs[w][(quad * 4 + j) * 64 + dc * 16 + l16];
    f32x4 z = {};
    oacc[dc] = __builtin_amdgcn_mfma_f32_16x16x16f16(pa, vbf, z, 0, 0, 0);
  }

  const size_t obase =
      ((size_t)(n4 << 12) + (size_t)(s >> 4)) * Edim + (size_t)(s & 15) * 64 + l16;
#pragma unroll
  for (int reg = 0; reg < 4; reg++) {
    const size_t rowoff = obase + (size_t)(quad * 4 + reg) * 256 * Edim;
#pragma unroll
    for (int dc = 0; dc < 4; dc++)
      Ab[rowoff + dc * 16] = (f16_t)oacc[dc][reg];
  }
}

// ---------------- launcher ----------------
extern "C" void kernel_launch(void* const* d_in, const int* in_sizes, int n_in,
                              void* d_out, int out_size, void* d_ws, size_t ws_size,
                              hipStream_t stream) {
  const float* x  = (const float*)d_in[0];
  const float* Wq = (const float*)d_in[1];
  const float* bq = (const float*)d_in[2];
  const float* Wk = (const float*)d_in[3];
  const float* bk = (const float*)d_in[4];
  const float* Wv = (const float*)d_in[5];
  const float* bv = (const float*)d_in[6];
  const float* Wo = (const float*)d_in[7];
  const float* bo = (const float*)d_in[8];
  float* out = (float*)d_out;

  f16_t* xh  = (f16_t*)d_ws;          // 33.5 MB
  f16_t* Wqh = xh + MATEL;            // 2 MB each
  f16_t* Wkh = Wqh + WEL;
  f16_t* Wvh = Wkh + WEL;
  f16_t* Woh = Wvh + WEL;
  f16_t* Qb  = Woh + WEL;             // 33.5 MB each
  f16_t* Kb  = Qb + MATEL;
  f16_t* Vb  = Kb + MATEL;
  f16_t* Ab  = Vb + MATEL;            // total ~176 MB

  cvt_kernel<<<dim3(2048, 5), dim3(256), 0, stream>>>(x, Wq, Wk, Wv, Wo,
                                                      xh, Wqh, Wkh, Wvh, Woh);
  const int ngrid = (Mrows / BM2) * (Edim / BN2);  // 64*4 = 256, %8 == 0
  qkv_kernel<<<dim3(ngrid, 1, 3), dim3(512), 0, stream>>>(
      xh, Wqh, bq, Wkh, bk, Wvh, bv, Qb, Kb, Vb);
  attn_kernel<<<dim3(Mrows / 4), dim3(256), 0, stream>>>(Qb, Kb, Vb, Ab);
  outp_kernel<<<dim3(ngrid), dim3(512), 0, stream>>>(Ab, Woh, bo, out);
}

// Round 2
// 330.789 us; speedup vs baseline: 1.0017x; 1.0017x over previous
//
#include <hip/hip_runtime.h>
#include <hip/hip_fp16.h>
#include <stddef.h>
#include <stdint.h>

// Problem: N=4, S=4096, E=1024, H=16, D=64. fp32 in/out.
// Reference = "attention over heads": per (n,s) position, 16x16 softmax across
// heads, then scrambled (N,H,S,D)->(N,S,E) reshape + output projection.
// Pipeline (f16 MFMA compute, fp32 accumulate; absmax ~8e-3 << 4.09e-2):
//   K0: convert x, Wq..Wo fp32 -> f16 in ws
//   K1: QKV projections (3x GEMM 16384x1024x1024 NT +bias) -> ws f16
//   K2: per-position head-attention, ONE WAVE per position (unchanged)
//   K3: output projection -> fp32 out
// GEMM core: 256x256 tile, BK=64, 8 waves, 8-phase counted-vmcnt schedule.
// ROUND-1 FIX: fragment loads are inline-asm ds_read_b128 on raw 32-bit LDS
// addresses. Plain C++ ds_reads with runtime (ha/hb/swizzle) offsets made the
// backend insert conservative vmcnt waits against outstanding global_load_lds
// (LDS-DMA alias), degenerating the pipeline to drain-0 (MfmaUtil 32%).

typedef _Float16 f16_t;
typedef _Float16 f16x8 __attribute__((ext_vector_type(8)));
typedef _Float16 f16x4 __attribute__((ext_vector_type(4)));
typedef float    f32x4 __attribute__((ext_vector_type(4)));

static constexpr int Sdim = 4096;
static constexpr int Edim = 1024;
static constexpr int Mrows = 4 * Sdim;                  // 16384
static constexpr size_t MATEL = (size_t)Mrows * Edim;   // 16.7M
static constexpr size_t WEL = (size_t)Edim * Edim;      // 1.05M

__device__ __forceinline__ void gload_lds16(const f16_t* g, f16_t* l) {
  // async global->LDS, 16B/lane; LDS dest = wave-uniform base + lane*16
  __builtin_amdgcn_global_load_lds(
      (const __attribute__((address_space(1))) void*)g,
      (__attribute__((address_space(3))) void*)l, 16, 0, 0);
}

// Opaque LDS read: backend cannot see an as(3) access -> no auto-inserted
// vmcnt waits vs in-flight LDS-DMA. MUST be volatile (ordering vs the
// "memory"-clobber waitcnt asms is what makes the hand schedule hold).
__device__ __forceinline__ f16x8 ds_read16(uint32_t byte_addr) {
  f16x8 r;
  asm volatile("ds_read_b128 %0, %1" : "=v"(r) : "v"(byte_addr));
  return r;
}

// ---------------- fp32 -> f16 convert ----------------
__global__ __launch_bounds__(256) void cvt_kernel(
    const float* __restrict__ s0, const float* __restrict__ s1,
    const float* __restrict__ s2, const float* __restrict__ s3,
    const float* __restrict__ s4,
    f16_t* __restrict__ d0, f16_t* __restrict__ d1, f16_t* __restrict__ d2,
    f16_t* __restrict__ d3, f16_t* __restrict__ d4) {
  const float* s; f16_t* d; size_t nv;  // nv = count of float4 groups
  switch (blockIdx.y) {
    case 0: s = s0; d = d0; nv = MATEL / 4; break;
    case 1: s = s1; d = d1; nv = WEL / 4; break;
    case 2: s = s2; d = d2; nv = WEL / 4; break;
    case 3: s = s3; d = d3; nv = WEL / 4; break;
    default: s = s4; d = d4; nv = WEL / 4; break;
  }
  const size_t stride = (size_t)gridDim.x * 256;
  for (size_t i = blockIdx.x * 256 + threadIdx.x; i < nv; i += stride) {
    const f32x4 v = ((const f32x4*)s)[i];
    f16x4 h;
#pragma unroll
    for (int j = 0; j < 4; j++) h[j] = (f16_t)v[j];
    ((f16x4*)d)[i] = h;
  }
}

// ---------------- 256^2 8-phase GEMM core ----------------
// C[m,n] = sum_k A[m,k]*B[n,k] + bias[n]  (NT, both row-major stride Edim)
// 512 threads = 8 waves (2M x 4N). Per wave: 128x64 output = acc[8][4] f32x4.
// LDS 128 KiB: [slot][mat A/B][half 128x64] double-buffered at K-tile (BK=64).
// Swizzle: logical (r,c) stored at f16 idx r*64 + (c ^ ((r&7)<<3)); applied as
// inverse on the per-lane GLOBAL source col (linear LDS dest) + on reads.
static constexpr int BM2 = 256, BN2 = 256, BK2 = 64;
static constexpr int NT2 = Edim / BK2;   // 16 K-tiles
static constexpr int HALF2 = 128 * BK2;  // 8192 f16 = 16KB per half-tile

template <int V> struct ic { static constexpr int v = V; };

template <typename TOut>
__device__ __forceinline__ void gemm256(const f16_t* __restrict__ A,
                                        const f16_t* __restrict__ B,
                                        const float* __restrict__ bias,
                                        TOut* __restrict__ C) {
  __shared__ __align__(16) f16_t lds[2][2][2][HALF2];  // [slot][mat][half][.]

  const int t = threadIdx.x;
  const int lane = t & 63;
  const int w = t >> 6;
  const int l16 = lane & 15;
  const int quad = lane >> 4;
  const int ha = w >> 2;         // A half this wave reads (wm = ha*128)
  const int hb = (w & 3) >> 1;   // B half this wave reads
  const int wnr = (w & 1) * 64;  // row offset inside B half

  // Raw 32-bit LDS byte base of the staging array (as(3) ptrtoint).
  const uint32_t ldsBase = (uint32_t)(uintptr_t)
      (__attribute__((address_space(3))) f16_t*)&lds[0][0][0][0];
  const uint32_t aHalfOff = (uint32_t)(ha * (HALF2 * 2));
  const uint32_t bHalfOff = (uint32_t)(32768 + hb * (HALF2 * 2));

  // T1: XCD-chunked bijective swizzle over the 256 (mtile,ntile) blocks.
  const int id = blockIdx.x;
  const int id2 = (id & 7) * 32 + (id >> 3);
  const int bm = (id2 & 63) * BM2;
  const int bn = (id2 >> 6) * BN2;

  // Staging geometry: per half-tile, 2 issues/wave, 1KB/wave/issue (linear).
  // phys f16 idx = w*512 + issue*4096 + lane*8 -> row w*8+issue*64+lane/8,
  // phys col (lane&7)*8; inverse-swizzled global col = ((lane&7)^((lane>>3)&7))*8.
  const int srow = w * 8 + (lane >> 3);
  const int scol = ((lane & 7) ^ ((lane >> 3) & 7)) * 8;
  const size_t gA0 = (size_t)(bm + srow) * Edim + scol;
  const size_t gB0 = (size_t)(bn + srow) * Edim + scol;
  const int lws = w * 512 + lane * 8;

  auto stage = [&](int mat, int half, int slot, int kt) {
    const f16_t* g = (mat == 0 ? A + gA0 : B + gB0) +
                     (size_t)half * 128 * Edim + kt * BK2;
    f16_t* l = &lds[slot][mat][half][lws];
    gload_lds16(g, l);                             // rows 0..63 of half
    gload_lds16(g + (size_t)64 * Edim, l + 4096);  // rows 64..127
  };

  f32x4 acc[8][4] = {};

  // Prologue: tile0 (A0,A1,B0,B1) + B(1). vmcnt(4) -> all of tile0 landed.
  stage(0, 0, 0, 0); stage(0, 1, 0, 0);
  stage(1, 0, 0, 0); stage(1, 1, 0, 0);
  stage(1, 0, 1, 1); stage(1, 1, 1, 1);
  asm volatile("s_waitcnt vmcnt(4)" ::: "memory");
  __builtin_amdgcn_s_barrier();
  asm volatile("" ::: "memory");

  // One K-tile = 4 phases: (kc0,ih0)(kc0,ih1)(kc1,ih0)(kc1,ih1).
  // ds-reads/phase: P1 = 4A+4B(kc0), P2 = 4A+4B(kc1), P3/P4 = 4A.
  // Stage schedule (write-safety proven vs barriers + lgkm waits):
  //   P1: A0(t+1)->slot^1   (slot^1 A last read at t-1's P4, lgkm-drained)
  //   P2: A1(t+1)->slot^1
  //   P3: B0(t+2)->slot     (slot B last read P2, lgkm-drained + barrier)
  //   P4: B1(t+2)->slot, then vmcnt(4): leaves only B(t+2) in flight
  //       -> A(t+1), B(t+1) guaranteed landed before tile t+1's P1 reads.
  auto ktile = [&](int tt, auto Sc, auto SAc, auto SBc, auto VNc) {
    constexpr int S = decltype(Sc)::v;
    constexpr int SA = decltype(SAc)::v;   // stage A(t+1)?
    constexpr int SB = decltype(SBc)::v;   // stage B(t+2)?
    constexpr int VN = decltype(VNc)::v;   // 1 -> vmcnt(4), 0 -> vmcnt(0)
    const uint32_t aB = ldsBase + (uint32_t)(S * 65536) + aHalfOff;
    const uint32_t bB = ldsBase + (uint32_t)(S * 65536) + bHalfOff;
    f16x8 bf[2][4];
#pragma unroll
    for (int kc = 0; kc < 2; ++kc) {
#pragma unroll
      for (int ih = 0; ih < 2; ++ih) {
        // B fragments: kc0's at P1, kc1's at P2 (lgkm-drained >=1 barrier
        // before the B(t+2) stages at P3/P4 touch the same LDS region).
        if (kc == 0) {
          const int kk = ih;
#pragma unroll
          for (int j = 0; j < 4; ++j) {
            const int r = wnr + j * 16 + l16;
            bf[kk][j] = ds_read16(
                bB + (uint32_t)((r * 64 + ((kk * 32 + quad * 8) ^
                                           ((r & 7) << 3))) * 2));
          }
        }
        f16x8 af[4];
#pragma unroll
        for (int ii = 0; ii < 4; ++ii) {
          const int r = ih * 64 + ii * 16 + l16;
          af[ii] = ds_read16(
              aB + (uint32_t)((r * 64 + ((kc * 32 + quad * 8) ^
                                         ((r & 7) << 3))) * 2));
        }
        if (kc == 0 && ih == 0) { if (SA) stage(0, 0, S ^ 1, tt + 1); }
        if (kc == 0 && ih == 1) { if (SA) stage(0, 1, S ^ 1, tt + 1); }
        if (kc == 1 && ih == 0) { if (SB) stage(1, 0, S, tt + 2); }
        if (kc == 1 && ih == 1) {
          if (SB) stage(1, 1, S, tt + 2);
          if (VN) asm volatile("s_waitcnt vmcnt(4)" ::: "memory");
          else    asm volatile("s_waitcnt vmcnt(0)" ::: "memory");
        }
        asm volatile("" ::: "memory");
        __builtin_amdgcn_s_barrier();
        asm volatile("s_waitcnt lgkmcnt(0)" ::: "memory");
        __builtin_amdgcn_sched_barrier(0);
        __builtin_amdgcn_s_setprio(1);
#pragma unroll
        for (int ii = 0; ii < 4; ++ii)
#pragma unroll
          for (int j = 0; j < 4; ++j)
            acc[ih * 4 + ii][j] = __builtin_amdgcn_mfma_f32_16x16x32_f16(
                af[ii], bf[kc][j], acc[ih * 4 + ii][j], 0, 0, 0);
        __builtin_amdgcn_s_setprio(0);
        __builtin_amdgcn_s_barrier();
        asm volatile("" ::: "memory");
      }
    }
  };

  for (int it = 0; it < NT2 / 2 - 1; ++it) {   // tiles 0..13, full pipeline
    ktile(2 * it,     ic<0>{}, ic<1>{}, ic<1>{}, ic<1>{});
    ktile(2 * it + 1, ic<1>{}, ic<1>{}, ic<1>{}, ic<1>{});
  }
  // Tail: tile 14 still stages A(15); no B stage; drain to vmcnt(0).
  ktile(NT2 - 2, ic<0>{}, ic<1>{}, ic<0>{}, ic<0>{});
  ktile(NT2 - 1, ic<1>{}, ic<0>{}, ic<0>{}, ic<0>{});

  // Epilogue. C/D layout: col = lane&15, row = quad*4 + reg [m89-verified].
  const int wm = ha * 128;
  const int wn = (w & 3) * 64;
#pragma unroll
  for (int j = 0; j < 4; ++j) {
    const int col = bn + wn + j * 16 + l16;
    const float bv = bias[col];
#pragma unroll
    for (int i = 0; i < 8; ++i) {
      const int rb = bm + wm + i * 16 + quad * 4;
#pragma unroll
      for (int r = 0; r < 4; ++r)
        C[(size_t)(rb + r) * Edim + col] = (TOut)(acc[i][j][r] + bv);
    }
  }
}

__global__ __launch_bounds__(512, 2) void qkv_kernel(
    const f16_t* __restrict__ x,
    const f16_t* __restrict__ Wq, const float* __restrict__ bq,
    const f16_t* __restrict__ Wk, const float* __restrict__ bk,
    const f16_t* __restrict__ Wv, const float* __restrict__ bv,
    f16_t* __restrict__ Qb, f16_t* __restrict__ Kb, f16_t* __restrict__ Vb) {
  const f16_t* W; const float* bi; f16_t* C;
  if (blockIdx.z == 0)      { W = Wq; bi = bq; C = Qb; }
  else if (blockIdx.z == 1) { W = Wk; bi = bk; C = Kb; }
  else                      { W = Wv; bi = bv; C = Vb; }
  gemm256<f16_t>(x, W, bi, C);
}

__global__ __launch_bounds__(512, 2) void outp_kernel(
    const f16_t* __restrict__ Ab, const f16_t* __restrict__ Wo,
    const float* __restrict__ bo, float* __restrict__ out) {
  gemm256<float>(Ab, Wo, bo, out);
}

// ---------------- per-position head-attention (one wave / position) ----------
// (unchanged from verified kernel)
__global__ __launch_bounds__(256) void attn_kernel(const f16_t* __restrict__ Qb,
                                                   const f16_t* __restrict__ Kb,
                                                   const f16_t* __restrict__ Vb,
                                                   f16_t* __restrict__ Ab) {
  __shared__ __align__(16) f16_t Vs[4][1024];  // per-wave V row (2KB each)
  const int t = threadIdx.x;
  const int w = t >> 6;
  const int lane = t & 63;
  const int l16 = lane & 15;
  const int quad = lane >> 4;
  const int pos = blockIdx.x * 4 + w;           // n*S + s
  const int n4 = pos >> 12;
  const int s = pos & (Sdim - 1);

  const f16_t* Qr = Qb + (size_t)pos * Edim;
  const f16_t* Kr = Kb + (size_t)pos * Edim;
  const f16_t* Vr = Vb + (size_t)pos * Edim;

  *(f16x8*)&Vs[w][lane * 16]     = *(const f16x8*)(Vr + lane * 16);
  *(f16x8*)&Vs[w][lane * 16 + 8] = *(const f16x8*)(Vr + lane * 16 + 8);

  f32x4 sacc = {};
#pragma unroll
  for (int step = 0; step < 2; step++) {
    const int off = l16 * 64 + step * 32 + quad * 8;
    const f16x8 kf = *(const f16x8*)(Kr + off);  // A: K[m=l16][k]
    const f16x8 qf = *(const f16x8*)(Qr + off);  // B: Q[n=l16][k]
    sacc = __builtin_amdgcn_mfma_f32_16x16x32_f16(kf, qf, sacc, 0, 0, 0);
  }
#pragma unroll
  for (int r = 0; r < 4; r++) sacc[r] *= 0.125f;

  float m = fmaxf(fmaxf(sacc[0], sacc[1]), fmaxf(sacc[2], sacc[3]));
  m = fmaxf(m, __shfl_xor(m, 16));
  m = fmaxf(m, __shfl_xor(m, 32));
  float e[4];
#pragma unroll
  for (int r = 0; r < 4; r++) e[r] = __expf(sacc[r] - m);
  float l = (e[0] + e[1]) + (e[2] + e[3]);
  l += __shfl_xor(l, 16);
  l += __shfl_xor(l, 32);
  const float inv = 1.0f / l;
  f16x4 pa;
#pragma unroll
  for (int r = 0; r < 4; r++) pa[r] = (f16_t)(e[r] * inv);

  __syncthreads();
  f32x4 oacc[4];
#pragma unroll
  for (int dc = 0; dc < 4; dc++) {
    f16x4 vbf;
#pragma unroll
    for (int j = 0; j < 4; j++)
      vbf[j] = Vs[w][(quad * 4 + j) * 64 + dc * 16 + l16];
    f32x4 z = {};
    oacc[dc] = __builtin_amdgcn_mfma_f32_16x16x16f16(pa, vbf, z, 0, 0, 0);
  }

  const size_t obase =
      ((size_t)(n4 << 12) + (size_t)(s >> 4)) * Edim + (size_t)(s & 15) * 64 + l16;
#pragma unroll
  for (int reg = 0; reg < 4; reg++) {
    const size_t rowoff = obase + (size_t)(quad * 4 + reg) * 256 * Edim;
#pragma unroll
    for (int dc = 0; dc < 4; dc++)
      Ab[rowoff + dc * 16] = (f16_t)oacc[dc][reg];
  }
}

// ---------------- launcher ----------------
extern "C" void kernel_launch(void* const* d_in, const int* in_sizes, int n_in,
                              void* d_out, int out_size, void* d_ws, size_t ws_size,
                              hipStream_t stream) {
  const float* x  = (const float*)d_in[0];
  const float* Wq = (const float*)d_in[1];
  const float* bq = (const float*)d_in[2];
  const float* Wk = (const float*)d_in[3];
  const float* bk = (const float*)d_in[4];
  const float* Wv = (const float*)d_in[5];
  const float* bv = (const float*)d_in[6];
  const float* Wo = (const float*)d_in[7];
  const float* bo = (const float*)d_in[8];
  float* out = (float*)d_out;

  f16_t* xh  = (f16_t*)d_ws;          // 33.5 MB
  f16_t* Wqh = xh + MATEL;            // 2 MB each
  f16_t* Wkh = Wqh + WEL;
  f16_t* Wvh = Wkh + WEL;
  f16_t* Woh = Wvh + WEL;
  f16_t* Qb  = Woh + WEL;             // 33.5 MB each
  f16_t* Kb  = Qb + MATEL;
  f16_t* Vb  = Kb + MATEL;
  f16_t* Ab  = Vb + MATEL;            // total ~176 MB

  cvt_kernel<<<dim3(2048, 5), dim3(256), 0, stream>>>(x, Wq, Wk, Wv, Wo,
                                                      xh, Wqh, Wkh, Wvh, Woh);
  const int ngrid = (Mrows / BM2) * (Edim / BN2);  // 64*4 = 256, %8 == 0
  qkv_kernel<<<dim3(ngrid, 1, 3), dim3(512), 0, stream>>>(
      xh, Wqh, bq, Wkh, bk, Wvh, bv, Qb, Kb, Vb);
  attn_kernel<<<dim3(Mrows / 4), dim3(256), 0, stream>>>(Qb, Kb, Vb, Ab);
  outp_kernel<<<dim3(ngrid), dim3(512), 0, stream>>>(Ab, Woh, bo, out);
}